// Round 2
// baseline (6327.934 us; speedup 1.0000x reference)
//
#include <hip/hip_runtime.h>
#include <math.h>

#define KB       2            // blocks
#define NTHREADS 1024
#define HID      4096
#define HB       (HID / KB)   // 2048 neurons per block
#define TT       1000
#define PP       16

#define BETA 0.9f
#define THRV 0.5f
#define DTV  0.005f

// ws layout: u64 slots[2 parity][2 block][16]  (512 bytes)
__global__ void zero_kernel(unsigned long long* slots, float* out) {
    int i = blockIdx.x * blockDim.x + threadIdx.x;
    if (i < 2 * KB * PP) slots[i] = 0ull;       // tag 0 never matches t>=1
    if (i < 2 * TT) out[i] = 0.f;
}

__global__ __launch_bounds__(NTHREADS, 1)
void snn_kernel(const float* __restrict__ x,
                const float* __restrict__ noise,
                const float* __restrict__ Win,
                const float* __restrict__ Wout,
                const float* __restrict__ pin,
                const float* __restrict__ pout,
                const float* __restrict__ lvec,
                const float* __restrict__ stdv,
                float* __restrict__ out,
                unsigned long long* __restrict__ slots)
{
    const int b    = blockIdx.x;
    const int ob   = 1 - b;
    const int tid  = threadIdx.x;
    const int wave = tid >> 6;
    const int lane = tid & 63;
    const int h0   = b * HB + tid * 2;   // two consecutive neurons per thread
    const int h1   = h0 + 1;

    __shared__ float part[16][20];       // [wave][18 values, padded to 20]
    __shared__ float ubuf[16][16];       // per-wave u broadcast area

    // ---------------- parameter load (once) ----------------
    float lv[PP];
    #pragma unroll
    for (int p = 0; p < PP; p += 4) {
        float4 t4 = *(const float4*)&lvec[p];
        lv[p] = t4.x; lv[p+1] = t4.y; lv[p+2] = t4.z; lv[p+3] = t4.w;
    }
    float pl0[PP], pl1[PP], po0[PP], po1[PP];
    #pragma unroll
    for (int p = 0; p < PP; p += 4) {
        float4 a = *(const float4*)&pin[h0*PP + p];
        float4 c = *(const float4*)&pin[h1*PP + p];
        pl0[p]   = a.x*lv[p];   pl0[p+1] = a.y*lv[p+1];
        pl0[p+2] = a.z*lv[p+2]; pl0[p+3] = a.w*lv[p+3];
        pl1[p]   = c.x*lv[p];   pl1[p+1] = c.y*lv[p+1];
        pl1[p+2] = c.z*lv[p+2]; pl1[p+3] = c.w*lv[p+3];
        float4 e = *(const float4*)&pout[h0*PP + p];
        float4 f = *(const float4*)&pout[h1*PP + p];
        po0[p]   = e.x; po0[p+1] = e.y; po0[p+2] = e.z; po0[p+3] = e.w;
        po1[p]   = f.x; po1[p+1] = f.y; po1[p+2] = f.z; po1[p+3] = f.w;
    }
    const float2* win2 = (const float2*)Win;          // Win row h = float2 idx h*3..h*3+2
    float2 wa0 = win2[h0*3], wb0 = win2[h0*3+1], wc0 = win2[h0*3+2];
    float2 wa1 = win2[h1*3], wb1 = win2[h1*3+1], wc1 = win2[h1*3+2];
    float2 wo_a = *(const float2*)&Wout[h0];          // Wout[0][h0..h1]
    float2 wo_b = *(const float2*)&Wout[HID + h0];    // Wout[1][h0..h1]

    float2 sd = *(const float2*)&stdv[h0];
    float sig0 = 1.f / (1.f + expf(-sd.x));
    float sig1 = 1.f / (1.f + expf(-sd.y));
    float tau0 = sig0 * 0.03f + 0.02f;
    float tau1 = sig1 * 0.03f + 0.02f;
    float dd0  = expf(-DTV / tau0);
    float dd1  = expf(-DTV / tau1);
    float sg0  = DTV / (tau0 * 0.002f);
    float sg1  = DTV / (tau1 * 0.002f);
    const float DECAY_R = expf(-2.5f);

    // ---------------- state ----------------
    float mem0 = 0.f, mem1 = 0.f, r0 = 0.f, r1 = 0.f, s0 = 0.f, s1 = 0.f;

    const float2* x2 = (const float2*)x;
    float2 nz = *(const float2*)&noise[h0];           // t = 0
    float2 xa = x2[0], xb = x2[1], xc = x2[2];

    for (int t = 0; t < TT; ++t) {
        // prefetch next step's inputs (overlaps sync below)
        const int tn = (t + 1 < TT) ? t + 1 : t;
        float2 nz_n = *(const float2*)&noise[tn * HID + h0];
        float2 xa_n = x2[tn*3], xb_n = x2[tn*3+1], xc_n = x2[tn*3+2];

        float uu[16];
        if (t > 0) {
            const int par = t & 1;
            // ---- phase A: 18-value wave butterfly of r_{t-1} products ----
            float pa[18];
            #pragma unroll
            for (int p = 0; p < PP; ++p) pa[p] = po0[p]*r0 + po1[p]*r1;
            pa[16] = wo_a.x*r0 + wo_a.y*r1;
            pa[17] = wo_b.x*r0 + wo_b.y*r1;
            #pragma unroll
            for (int m = 1; m < 64; m <<= 1) {
                #pragma unroll
                for (int j = 0; j < 18; ++j) pa[j] += __shfl_xor(pa[j], m, 64);
            }
            if (lane == 0) {
                float* pw = &part[wave][0];
                *(float4*)&pw[0]  = make_float4(pa[0],pa[1],pa[2],pa[3]);
                *(float4*)&pw[4]  = make_float4(pa[4],pa[5],pa[6],pa[7]);
                *(float4*)&pw[8]  = make_float4(pa[8],pa[9],pa[10],pa[11]);
                *(float4*)&pw[12] = make_float4(pa[12],pa[13],pa[14],pa[15]);
                *(float2*)&pw[16] = make_float2(pa[16],pa[17]);
            }
            __syncthreads();

            // ---- every wave: block sum from LDS (bit-identical across waves) ----
            float bs = 0.f;
            if (lane < 18) {
                #pragma unroll
                for (int w = 0; w < 16; ++w) bs += part[w][lane];
            }

            // ---- wave 0: publish tagged partials + y output ----
            if (wave == 0) {
                if (lane < PP) {
                    union { float f; unsigned u; } cv; cv.f = bs;
                    unsigned long long pk = ((unsigned long long)(unsigned)t << 32)
                                          | (unsigned long long)cv.u;
                    __hip_atomic_store(&slots[(size_t)(par*KB + b)*PP + lane], pk,
                                       __ATOMIC_RELAXED, __HIP_MEMORY_SCOPE_AGENT);
                } else if (lane < 18) {
                    atomicAdd(&out[(t-1)*2 + (lane-16)], bs);
                }
            }

            // ---- all waves: poll remote block's tagged slot (1 u64 per lane<16) ----
            float rem = 0.f;
            if (lane < PP) {
                const unsigned long long* rp = &slots[(size_t)(par*KB + ob)*PP + lane];
                unsigned long long v;
                int spin = 0;
                do {
                    v = __hip_atomic_load(rp, __ATOMIC_RELAXED,
                                          __HIP_MEMORY_SCOPE_AGENT);
                } while ((int)(v >> 32) != t && ++spin < (1 << 20));
                union { unsigned u; float f; } cv; cv.u = (unsigned)v;
                rem = cv.f;
            }
            float usum = bs + rem;                 // commutative: identical both blocks
            if (lane < PP) ubuf[wave][lane] = usum;
            float4 u0 = *(const float4*)&ubuf[wave][0];
            float4 u1 = *(const float4*)&ubuf[wave][4];
            float4 u2 = *(const float4*)&ubuf[wave][8];
            float4 u3 = *(const float4*)&ubuf[wave][12];
            uu[0]=u0.x; uu[1]=u0.y; uu[2]=u0.z; uu[3]=u0.w;
            uu[4]=u1.x; uu[5]=u1.y; uu[6]=u1.z; uu[7]=u1.w;
            uu[8]=u2.x; uu[9]=u2.y; uu[10]=u2.z; uu[11]=u2.w;
            uu[12]=u3.x; uu[13]=u3.y; uu[14]=u3.z; uu[15]=u3.w;
        } else {
            #pragma unroll
            for (int p = 0; p < 16; ++p) uu[p] = 0.f;
        }

        // ---- phase E: per-neuron update ----
        float rec0 = 0.f, rec1 = 0.f;
        #pragma unroll
        for (int p = 0; p < PP; ++p) { rec0 += pl0[p]*uu[p]; rec1 += pl1[p]*uu[p]; }
        float xw0 = wa0.x*xa.x + wa0.y*xa.y + wb0.x*xb.x + wb0.y*xb.y
                  + wc0.x*xc.x + wc0.y*xc.y;
        float xw1 = wa1.x*xa.x + wa1.y*xa.y + wb1.x*xb.x + wb1.y*xb.y
                  + wc1.x*xc.x + wc1.y*xc.y;
        float I0 = (xw0 + rec0) + nz.x / 10.0f;
        float I1 = (xw1 + rec1) + nz.y / 10.0f;

        float rst0 = (mem0 - THRV > 0.f) ? THRV : 0.f;   // reset from incoming mem
        float rst1 = (mem1 - THRV > 0.f) ? THRV : 0.f;
        mem0 = BETA*mem0 + I0 - rst0;
        mem1 = BETA*mem1 + I1 - rst1;
        float spk0 = (mem0 - THRV > 0.f) ? 1.f : 0.f;
        float spk1 = (mem1 - THRV > 0.f) ? 1.f : 0.f;
        s0 = s0*DECAY_R + sg0*spk0;
        s1 = s1*DECAY_R + sg1*spk1;
        r0 = dd0*r0 + DTV*s0;
        r1 = dd1*r1 + DTV*s1;

        nz = nz_n; xa = xa_n; xb = xb_n; xc = xc_n;
    }

    // ---- final y[T-1] from r_{T-1} (no cross-block sync needed) ----
    {
        float ya = wo_a.x*r0 + wo_a.y*r1;
        float yb = wo_b.x*r0 + wo_b.y*r1;
        #pragma unroll
        for (int m = 1; m < 64; m <<= 1) {
            ya += __shfl_xor(ya, m, 64);
            yb += __shfl_xor(yb, m, 64);
        }
        if (lane == 0) {
            atomicAdd(&out[(TT-1)*2 + 0], ya);
            atomicAdd(&out[(TT-1)*2 + 1], yb);
        }
    }
}

extern "C" void kernel_launch(void* const* d_in, const int* in_sizes, int n_in,
                              void* d_out, int out_size, void* d_ws, size_t ws_size,
                              hipStream_t stream)
{
    const float* x     = (const float*)d_in[0];
    const float* noise = (const float*)d_in[1];
    const float* Win   = (const float*)d_in[2];
    const float* Wout  = (const float*)d_in[3];
    const float* pin   = (const float*)d_in[4];
    const float* pout  = (const float*)d_in[5];
    const float* l     = (const float*)d_in[6];
    const float* stdv  = (const float*)d_in[7];
    float* out = (float*)d_out;
    unsigned long long* slots = (unsigned long long*)d_ws;

    hipLaunchKernelGGL(zero_kernel, dim3(2), dim3(1024), 0, stream, slots, out);
    hipLaunchKernelGGL(snn_kernel, dim3(KB), dim3(NTHREADS), 0, stream,
                       x, noise, Win, Wout, pin, pout, l, stdv,
                       out, slots);
}

// Round 3
// 1679.170 us; speedup vs baseline: 3.7685x; 3.7685x over previous
//
#include <hip/hip_runtime.h>
#include <math.h>

#define KB       4            // blocks
#define NTHREADS 512
#define NW       (NTHREADS/64)
#define HID      4096
#define HB       (HID / KB)   // 1024 neurons per block
#define TT       1000
#define PP       16
#define SLOTW    24           // padded u64 stride per block-slot

#define BETA 0.9f
#define THRV 0.5f
#define DTV  0.005f

__global__ __launch_bounds__(NTHREADS, 1)
void snn_kernel(const float* __restrict__ x,
                const float* __restrict__ noise,
                const float* __restrict__ Win,
                const float* __restrict__ Wout,
                const float* __restrict__ pin,
                const float* __restrict__ pout,
                const float* __restrict__ lvec,
                const float* __restrict__ stdv,
                float* __restrict__ out,
                unsigned long long* __restrict__ slots)
{
    const int b    = blockIdx.x;
    const int tid  = threadIdx.x;
    const int wave = tid >> 6;
    const int lane = tid & 63;
    const int h0   = b * HB + tid * 2;   // two consecutive neurons per thread
    const int h1   = h0 + 1;

    const bool lb0 = (lane & 1) != 0;
    const bool lb1 = (lane & 2) != 0;
    const bool lb2 = (lane & 4) != 0;
    const bool lb3 = (lane & 8) != 0;

    // remote block indices in ascending order
    const int rb0 = (b == 0) ? 1 : 0;
    const int rb1 = (b <= 1) ? 2 : 1;
    const int rb2 = (b <= 2) ? 3 : 2;

    __shared__ float part[NW][20];       // [wave][18 values, padded]
    __shared__ float ubuf[NW][16];       // per-wave u broadcast area

    // ---------------- parameter load (once) ----------------
    float lv[PP];
    #pragma unroll
    for (int p = 0; p < PP; p += 4) {
        float4 t4 = *(const float4*)&lvec[p];
        lv[p] = t4.x; lv[p+1] = t4.y; lv[p+2] = t4.z; lv[p+3] = t4.w;
    }
    float pl0[PP], pl1[PP], po0[PP], po1[PP];
    #pragma unroll
    for (int p = 0; p < PP; p += 4) {
        float4 a = *(const float4*)&pin[h0*PP + p];
        float4 c = *(const float4*)&pin[h1*PP + p];
        pl0[p]   = a.x*lv[p];   pl0[p+1] = a.y*lv[p+1];
        pl0[p+2] = a.z*lv[p+2]; pl0[p+3] = a.w*lv[p+3];
        pl1[p]   = c.x*lv[p];   pl1[p+1] = c.y*lv[p+1];
        pl1[p+2] = c.z*lv[p+2]; pl1[p+3] = c.w*lv[p+3];
        float4 e = *(const float4*)&pout[h0*PP + p];
        float4 f = *(const float4*)&pout[h1*PP + p];
        po0[p]   = e.x; po0[p+1] = e.y; po0[p+2] = e.z; po0[p+3] = e.w;
        po1[p]   = f.x; po1[p+1] = f.y; po1[p+2] = f.z; po1[p+3] = f.w;
    }
    const float2* win2 = (const float2*)Win;
    float2 wa0 = win2[h0*3], wb0 = win2[h0*3+1], wc0 = win2[h0*3+2];
    float2 wa1 = win2[h1*3], wb1 = win2[h1*3+1], wc1 = win2[h1*3+2];
    float2 wo_a = *(const float2*)&Wout[h0];
    float2 wo_b = *(const float2*)&Wout[HID + h0];

    float2 sd = *(const float2*)&stdv[h0];
    float sig0 = 1.f / (1.f + expf(-sd.x));
    float sig1 = 1.f / (1.f + expf(-sd.y));
    float tau0 = sig0 * 0.03f + 0.02f;
    float tau1 = sig1 * 0.03f + 0.02f;
    float dd0  = expf(-DTV / tau0);
    float dd1  = expf(-DTV / tau1);
    float sg0  = DTV / (tau0 * 0.002f);
    float sg1  = DTV / (tau1 * 0.002f);
    const float DECAY_R = expf(-2.5f);

    // ---------------- state ----------------
    float mem0 = 0.f, mem1 = 0.f, r0 = 0.f, r1 = 0.f, s0 = 0.f, s1 = 0.f;

    const float2* x2 = (const float2*)x;
    float2 nz = *(const float2*)&noise[h0];           // t = 0
    float2 xa = x2[0], xb = x2[1], xc = x2[2];

    float uu[16];
    #pragma unroll
    for (int p = 0; p < 16; ++p) uu[p] = 0.f;

    for (int t = 0; t <= TT; ++t) {
        // prefetch next step's inputs (overlaps exchange below)
        float2 nz_n = nz, xa_n = xa, xb_n = xb, xc_n = xc;
        if (t < TT - 1) {
            const int tn = t + 1;
            nz_n = *(const float2*)&noise[tn * HID + h0];
            xa_n = x2[tn*3]; xb_n = x2[tn*3+1]; xc_n = x2[tn*3+2];
        }

        if (t > 0) {
            const int par = t & 1;
            // ---- pa: 18 per-thread partials from r_{t-1} ----
            float pa[18];
            #pragma unroll
            for (int p = 0; p < PP; ++p) pa[p] = po0[p]*r0 + po1[p]*r1;
            pa[16] = wo_a.x*r0 + wo_a.y*r1;
            pa[17] = wo_b.x*r0 + wo_b.y*r1;

            // ---- reduce-scatter butterfly: lane ends with u[lane&15], y[lane&1] ----
            float a1[8], yv;
            #pragma unroll
            for (int k = 0; k < 8; ++k) {
                float keep = lb0 ? pa[2*k+1] : pa[2*k];
                float send = lb0 ? pa[2*k]   : pa[2*k+1];
                a1[k] = keep + __shfl_xor(send, 1, 64);
            }
            {
                float keep = lb0 ? pa[17] : pa[16];
                float send = lb0 ? pa[16] : pa[17];
                yv = keep + __shfl_xor(send, 1, 64);
            }
            float a2[4];
            #pragma unroll
            for (int k = 0; k < 4; ++k) {
                float keep = lb1 ? a1[2*k+1] : a1[2*k];
                float send = lb1 ? a1[2*k]   : a1[2*k+1];
                a2[k] = keep + __shfl_xor(send, 2, 64);
            }
            yv += __shfl_xor(yv, 2, 64);
            float a3[2];
            #pragma unroll
            for (int k = 0; k < 2; ++k) {
                float keep = lb2 ? a2[2*k+1] : a2[2*k];
                float send = lb2 ? a2[2*k]   : a2[2*k+1];
                a3[k] = keep + __shfl_xor(send, 4, 64);
            }
            yv += __shfl_xor(yv, 4, 64);
            float uv;
            {
                float keep = lb3 ? a3[1] : a3[0];
                float send = lb3 ? a3[0] : a3[1];
                uv = keep + __shfl_xor(send, 8, 64);
            }
            yv += __shfl_xor(yv, 8, 64);
            uv += __shfl_xor(uv, 16, 64);
            uv += __shfl_xor(uv, 32, 64);
            yv += __shfl_xor(yv, 16, 64);
            yv += __shfl_xor(yv, 32, 64);

            // ---- per-wave partials to LDS ----
            if (lane < 18) part[wave][lane] = (lane < 16) ? uv : yv;
            __syncthreads();

            // ---- every wave: block sum (fixed tree, bit-identical) ----
            float bs = 0.f;
            if (lane < 18) {
                float q01 = part[0][lane] + part[1][lane];
                float q23 = part[2][lane] + part[3][lane];
                float q45 = part[4][lane] + part[5][lane];
                float q67 = part[6][lane] + part[7][lane];
                bs = (q01 + q23) + (q45 + q67);
            }

            // ---- wave 0: publish tagged partials ----
            if (wave == 0 && lane < 18) {
                union { float f; unsigned u; } cv; cv.f = bs;
                unsigned long long pk = ((unsigned long long)(unsigned)t << 32)
                                      | (unsigned long long)cv.u;
                __hip_atomic_store(&slots[(size_t)(par*KB + b)*SLOTW + lane], pk,
                                   __ATOMIC_RELAXED, __HIP_MEMORY_SCOPE_AGENT);
            }

            if (t < TT || b == 0) {
                // ---- poll 3 remote blocks' tagged slots ----
                float f0 = 0.f, f1 = 0.f, f2 = 0.f;
                if (lane < 18) {
                    const unsigned long long* p0 =
                        &slots[(size_t)(par*KB + rb0)*SLOTW + lane];
                    const unsigned long long* p1 =
                        &slots[(size_t)(par*KB + rb1)*SLOTW + lane];
                    const unsigned long long* p2 =
                        &slots[(size_t)(par*KB + rb2)*SLOTW + lane];
                    unsigned long long v0, v1, v2;
                    int spin = 0;
                    do {
                        v0 = __hip_atomic_load(p0, __ATOMIC_RELAXED,
                                               __HIP_MEMORY_SCOPE_AGENT);
                        v1 = __hip_atomic_load(p1, __ATOMIC_RELAXED,
                                               __HIP_MEMORY_SCOPE_AGENT);
                        v2 = __hip_atomic_load(p2, __ATOMIC_RELAXED,
                                               __HIP_MEMORY_SCOPE_AGENT);
                    } while ((((int)(v0 >> 32) != t) | ((int)(v1 >> 32) != t) |
                              ((int)(v2 >> 32) != t)) && ++spin < (1 << 20));
                    union { unsigned u; float f; } c0, c1, c2;
                    c0.u = (unsigned)v0; c1.u = (unsigned)v1; c2.u = (unsigned)v2;
                    f0 = c0.f; f1 = c1.f; f2 = c2.f;
                }
                // canonical block-order tree: (B0+B1)+(B2+B3), bit-identical everywhere
                float total = (b < 2) ? ((bs + f0) + (f1 + f2))
                                      : ((f0 + f1) + (f2 + bs));
                if (lane < 16) ubuf[wave][lane] = total;
                if (b == 0 && wave == 0 && lane >= 16 && lane < 18)
                    out[(t-1)*2 + (lane - 16)] = total;   // y[t-1]

                float4 u0 = *(const float4*)&ubuf[wave][0];
                float4 u1 = *(const float4*)&ubuf[wave][4];
                float4 u2 = *(const float4*)&ubuf[wave][8];
                float4 u3 = *(const float4*)&ubuf[wave][12];
                uu[0]=u0.x; uu[1]=u0.y; uu[2]=u0.z; uu[3]=u0.w;
                uu[4]=u1.x; uu[5]=u1.y; uu[6]=u1.z; uu[7]=u1.w;
                uu[8]=u2.x; uu[9]=u2.y; uu[10]=u2.z; uu[11]=u2.w;
                uu[12]=u3.x; uu[13]=u3.y; uu[14]=u3.z; uu[15]=u3.w;
            }
        }

        if (t < TT) {
            // ---- per-neuron update with x[t], noise[t], u_t ----
            float rec0 = 0.f, rec1 = 0.f;
            #pragma unroll
            for (int p = 0; p < PP; ++p) { rec0 += pl0[p]*uu[p]; rec1 += pl1[p]*uu[p]; }
            float xw0 = wa0.x*xa.x + wa0.y*xa.y + wb0.x*xb.x + wb0.y*xb.y
                      + wc0.x*xc.x + wc0.y*xc.y;
            float xw1 = wa1.x*xa.x + wa1.y*xa.y + wb1.x*xb.x + wb1.y*xb.y
                      + wc1.x*xc.x + wc1.y*xc.y;
            float I0 = (xw0 + rec0) + nz.x / 10.0f;
            float I1 = (xw1 + rec1) + nz.y / 10.0f;

            float rst0 = (mem0 - THRV > 0.f) ? THRV : 0.f;   // reset from incoming mem
            float rst1 = (mem1 - THRV > 0.f) ? THRV : 0.f;
            mem0 = BETA*mem0 + I0 - rst0;
            mem1 = BETA*mem1 + I1 - rst1;
            float spk0 = (mem0 - THRV > 0.f) ? 1.f : 0.f;
            float spk1 = (mem1 - THRV > 0.f) ? 1.f : 0.f;
            s0 = s0*DECAY_R + sg0*spk0;
            s1 = s1*DECAY_R + sg1*spk1;
            r0 = dd0*r0 + DTV*s0;
            r1 = dd1*r1 + DTV*s1;

            nz = nz_n; xa = xa_n; xb = xb_n; xc = xc_n;
        }
    }
}

extern "C" void kernel_launch(void* const* d_in, const int* in_sizes, int n_in,
                              void* d_out, int out_size, void* d_ws, size_t ws_size,
                              hipStream_t stream)
{
    const float* x     = (const float*)d_in[0];
    const float* noise = (const float*)d_in[1];
    const float* Win   = (const float*)d_in[2];
    const float* Wout  = (const float*)d_in[3];
    const float* pin   = (const float*)d_in[4];
    const float* pout  = (const float*)d_in[5];
    const float* l     = (const float*)d_in[6];
    const float* stdv  = (const float*)d_in[7];
    float* out = (float*)d_out;
    unsigned long long* slots = (unsigned long long*)d_ws;

    hipLaunchKernelGGL(snn_kernel, dim3(KB), dim3(NTHREADS), 0, stream,
                       x, noise, Win, Wout, pin, pout, l, stdv,
                       out, slots);
}

// Round 4
// 1630.519 us; speedup vs baseline: 3.8809x; 1.0298x over previous
//
#include <hip/hip_runtime.h>
#include <math.h>

#define KB       4            // blocks
#define NTHREADS 256
#define NW       4            // waves per block
#define HID      4096
#define HB       (HID / KB)   // 1024 neurons per block
#define NPT      4            // neurons per thread
#define TT       1000
#define PP       16
#define SLOTW    24           // padded u64 stride per block-slot

#define BETA 0.9f
#define THRV 0.5f
#define DTV  0.005f

// DPP cross-lane: quad_perm {1,0,3,2}=0xB1 (lane^1), {2,3,0,1}=0x4E (lane^2),
// row_ror:8 = 0x128 (lane^8 within row-of-16). All VALU-pipe (no DS).
template<int CTRL>
__device__ __forceinline__ float dppx(float v) {
    return __int_as_float(__builtin_amdgcn_update_dpp(
        0, __float_as_int(v), CTRL, 0xF, 0xF, true));
}

__global__ __launch_bounds__(NTHREADS, 1)
void snn_kernel(const float* __restrict__ x,
                const float* __restrict__ noise,
                const float* __restrict__ Win,
                const float* __restrict__ Wout,
                const float* __restrict__ pin,
                const float* __restrict__ pout,
                const float* __restrict__ lvec,
                const float* __restrict__ stdv,
                float* __restrict__ out,
                unsigned long long* __restrict__ slots)
{
    const int b    = blockIdx.x;
    const int tid  = threadIdx.x;
    const int wave = tid >> 6;
    const int lane = tid & 63;
    const int h0   = b * HB + tid * NPT;   // four consecutive neurons per thread

    const bool lb0 = (lane & 1) != 0;
    const bool lb1 = (lane & 2) != 0;
    const bool lb2 = (lane & 4) != 0;
    const bool lb3 = (lane & 8) != 0;

    // remote block indices in ascending order
    const int rb0 = (b == 0) ? 1 : 0;
    const int rb1 = (b <= 1) ? 2 : 1;
    const int rb2 = (b <= 2) ? 3 : 2;

    __shared__ float part[NW][20];       // [wave][18 values, padded]
    __shared__ float ubuf[NW][16];       // per-wave u broadcast area

    // ---------------- parameter load (once) ----------------
    float lv[PP];
    #pragma unroll
    for (int p = 0; p < PP; p += 4) {
        float4 t4 = *(const float4*)&lvec[p];
        lv[p] = t4.x; lv[p+1] = t4.y; lv[p+2] = t4.z; lv[p+3] = t4.w;
    }
    float pl[NPT][PP], po[NPT][PP];
    #pragma unroll
    for (int j = 0; j < NPT; ++j) {
        #pragma unroll
        for (int p = 0; p < PP; p += 4) {
            float4 a = *(const float4*)&pin[(h0+j)*PP + p];
            pl[j][p]   = a.x*lv[p];   pl[j][p+1] = a.y*lv[p+1];
            pl[j][p+2] = a.z*lv[p+2]; pl[j][p+3] = a.w*lv[p+3];
            float4 e = *(const float4*)&pout[(h0+j)*PP + p];
            po[j][p]   = e.x; po[j][p+1] = e.y;
            po[j][p+2] = e.z; po[j][p+3] = e.w;
        }
    }
    float win[NPT][6];
    #pragma unroll
    for (int j = 0; j < NPT; ++j) {
        const float2* wr = (const float2*)&Win[(h0+j)*6];
        float2 wA = wr[0], wB = wr[1], wC = wr[2];
        win[j][0]=wA.x; win[j][1]=wA.y; win[j][2]=wB.x;
        win[j][3]=wB.y; win[j][4]=wC.x; win[j][5]=wC.y;
    }
    float4 woa = *(const float4*)&Wout[h0];        // Wout[0][h0..h0+3]
    float4 wob = *(const float4*)&Wout[HID + h0];  // Wout[1][h0..h0+3]

    float4 sd4 = *(const float4*)&stdv[h0];
    float dd[NPT], sg[NPT];
    {
        float sdv[4] = { sd4.x, sd4.y, sd4.z, sd4.w };
        #pragma unroll
        for (int j = 0; j < NPT; ++j) {
            float sig = 1.f / (1.f + expf(-sdv[j]));
            float tau = sig * 0.03f + 0.02f;
            dd[j] = expf(-DTV / tau);
            sg[j] = DTV / (tau * 0.002f);
        }
    }
    const float DECAY_R = expf(-2.5f);

    // ---------------- state ----------------
    float mem[NPT], rr[NPT], ss[NPT];
    #pragma unroll
    for (int j = 0; j < NPT; ++j) { mem[j] = 0.f; rr[j] = 0.f; ss[j] = 0.f; }

    const float2* x2 = (const float2*)x;
    float4 nz = *(const float4*)&noise[h0];           // t = 0
    float2 xa = x2[0], xb = x2[1], xc = x2[2];

    float uu[16];
    #pragma unroll
    for (int p = 0; p < 16; ++p) uu[p] = 0.f;

    for (int t = 0; t <= TT; ++t) {
        // prefetch next step's inputs (overlaps exchange below)
        float4 nz_n = nz; float2 xa_n = xa, xb_n = xb, xc_n = xc;
        if (t < TT - 1) {
            const int tn = t + 1;
            nz_n = *(const float4*)&noise[tn * HID + h0];
            xa_n = x2[tn*3]; xb_n = x2[tn*3+1]; xc_n = x2[tn*3+2];
        }

        if (t > 0) {
            const int par = t & 1;
            // ---- pa: 18 per-thread partials from r_{t-1} (canonical tree) ----
            float pa[18];
            #pragma unroll
            for (int p = 0; p < PP; ++p)
                pa[p] = (po[0][p]*rr[0] + po[1][p]*rr[1])
                      + (po[2][p]*rr[2] + po[3][p]*rr[3]);
            pa[16] = (woa.x*rr[0] + woa.y*rr[1]) + (woa.z*rr[2] + woa.w*rr[3]);
            pa[17] = (wob.x*rr[0] + wob.y*rr[1]) + (wob.z*rr[2] + wob.w*rr[3]);

            // ---- reduce-scatter butterfly: lane ends with u[lane&15], y[lane&1] ----
            float a1[8], yv;
            #pragma unroll
            for (int k = 0; k < 8; ++k) {
                float keep = lb0 ? pa[2*k+1] : pa[2*k];
                float send = lb0 ? pa[2*k]   : pa[2*k+1];
                a1[k] = keep + dppx<0xB1>(send);          // xor1 (DPP)
            }
            {
                float keep = lb0 ? pa[17] : pa[16];
                float send = lb0 ? pa[16] : pa[17];
                yv = keep + dppx<0xB1>(send);
            }
            float a2[4];
            #pragma unroll
            for (int k = 0; k < 4; ++k) {
                float keep = lb1 ? a1[2*k+1] : a1[2*k];
                float send = lb1 ? a1[2*k]   : a1[2*k+1];
                a2[k] = keep + dppx<0x4E>(send);          // xor2 (DPP)
            }
            yv += dppx<0x4E>(yv);
            float a3[2];
            #pragma unroll
            for (int k = 0; k < 2; ++k) {
                float keep = lb2 ? a2[2*k+1] : a2[2*k];
                float send = lb2 ? a2[2*k]   : a2[2*k+1];
                a3[k] = keep + __shfl_xor(send, 4, 64);   // xor4 (DS)
            }
            yv += __shfl_xor(yv, 4, 64);
            float uv;
            {
                float keep = lb3 ? a3[1] : a3[0];
                float send = lb3 ? a3[0] : a3[1];
                uv = keep + dppx<0x128>(send);            // xor8 (DPP row_ror:8)
            }
            yv += dppx<0x128>(yv);
            uv += __shfl_xor(uv, 16, 64);                 // xor16 (DS)
            uv += __shfl_xor(uv, 32, 64);                 // xor32 (DS)
            yv += __shfl_xor(yv, 16, 64);
            yv += __shfl_xor(yv, 32, 64);

            // ---- per-wave partials to LDS ----
            if (lane < 18) part[wave][lane] = (lane < 16) ? uv : yv;
            __syncthreads();

            // ---- every wave: block sum (fixed tree, bit-identical) ----
            float bs = 0.f;
            if (lane < 18) {
                bs = (part[0][lane] + part[1][lane])
                   + (part[2][lane] + part[3][lane]);
            }

            // ---- wave 0: publish tagged partials ----
            if (wave == 0 && lane < 18) {
                union { float f; unsigned u; } cv; cv.f = bs;
                unsigned long long pk = ((unsigned long long)(unsigned)t << 32)
                                      | (unsigned long long)cv.u;
                __hip_atomic_store(&slots[(size_t)(par*KB + b)*SLOTW + lane], pk,
                                   __ATOMIC_RELAXED, __HIP_MEMORY_SCOPE_AGENT);
            }

            if (t < TT || b == 0) {
                // ---- poll 3 remote blocks' tagged slots ----
                float f0 = 0.f, f1 = 0.f, f2 = 0.f;
                if (lane < 18) {
                    const unsigned long long* p0 =
                        &slots[(size_t)(par*KB + rb0)*SLOTW + lane];
                    const unsigned long long* p1 =
                        &slots[(size_t)(par*KB + rb1)*SLOTW + lane];
                    const unsigned long long* p2 =
                        &slots[(size_t)(par*KB + rb2)*SLOTW + lane];
                    unsigned long long v0, v1, v2;
                    int spin = 0;
                    do {
                        v0 = __hip_atomic_load(p0, __ATOMIC_RELAXED,
                                               __HIP_MEMORY_SCOPE_AGENT);
                        v1 = __hip_atomic_load(p1, __ATOMIC_RELAXED,
                                               __HIP_MEMORY_SCOPE_AGENT);
                        v2 = __hip_atomic_load(p2, __ATOMIC_RELAXED,
                                               __HIP_MEMORY_SCOPE_AGENT);
                    } while ((((int)(v0 >> 32) != t) | ((int)(v1 >> 32) != t) |
                              ((int)(v2 >> 32) != t)) && ++spin < (1 << 20));
                    union { unsigned u; float f; } c0, c1, c2;
                    c0.u = (unsigned)v0; c1.u = (unsigned)v1; c2.u = (unsigned)v2;
                    f0 = c0.f; f1 = c1.f; f2 = c2.f;
                }
                // canonical block-order tree: (B0+B1)+(B2+B3), bit-identical everywhere
                float total = (b < 2) ? ((bs + f0) + (f1 + f2))
                                      : ((f0 + f1) + (f2 + bs));
                if (lane < 16) ubuf[wave][lane] = total;
                if (b == 0 && wave == 0 && lane >= 16 && lane < 18)
                    out[(t-1)*2 + (lane - 16)] = total;   // y[t-1]

                float4 u0 = *(const float4*)&ubuf[wave][0];
                float4 u1 = *(const float4*)&ubuf[wave][4];
                float4 u2 = *(const float4*)&ubuf[wave][8];
                float4 u3 = *(const float4*)&ubuf[wave][12];
                uu[0]=u0.x; uu[1]=u0.y; uu[2]=u0.z; uu[3]=u0.w;
                uu[4]=u1.x; uu[5]=u1.y; uu[6]=u1.z; uu[7]=u1.w;
                uu[8]=u2.x; uu[9]=u2.y; uu[10]=u2.z; uu[11]=u2.w;
                uu[12]=u3.x; uu[13]=u3.y; uu[14]=u3.z; uu[15]=u3.w;
            }
        }

        if (t < TT) {
            // ---- per-neuron update with x[t], noise[t], u_t ----
            float nzv[4] = { nz.x, nz.y, nz.z, nz.w };
            #pragma unroll
            for (int j = 0; j < NPT; ++j) {
                float ra = pl[j][0]*uu[0];
                float rb2_ = pl[j][8]*uu[8];
                #pragma unroll
                for (int p = 1; p < 8; ++p) {
                    ra   += pl[j][p]*uu[p];
                    rb2_ += pl[j][p+8]*uu[p+8];
                }
                float rec = ra + rb2_;
                float xw = win[j][0]*xa.x + win[j][1]*xa.y
                         + win[j][2]*xb.x + win[j][3]*xb.y
                         + win[j][4]*xc.x + win[j][5]*xc.y;
                float I = (xw + rec) + nzv[j] / 10.0f;

                float rst = (mem[j] - THRV > 0.f) ? THRV : 0.f; // reset from incoming mem
                mem[j] = BETA*mem[j] + I - rst;
                float spk = (mem[j] - THRV > 0.f) ? 1.f : 0.f;
                ss[j] = ss[j]*DECAY_R + sg[j]*spk;
                rr[j] = dd[j]*rr[j] + DTV*ss[j];
            }
            nz = nz_n; xa = xa_n; xb = xb_n; xc = xc_n;
        }
    }
}

extern "C" void kernel_launch(void* const* d_in, const int* in_sizes, int n_in,
                              void* d_out, int out_size, void* d_ws, size_t ws_size,
                              hipStream_t stream)
{
    const float* x     = (const float*)d_in[0];
    const float* noise = (const float*)d_in[1];
    const float* Win   = (const float*)d_in[2];
    const float* Wout  = (const float*)d_in[3];
    const float* pin   = (const float*)d_in[4];
    const float* pout  = (const float*)d_in[5];
    const float* l     = (const float*)d_in[6];
    const float* stdv  = (const float*)d_in[7];
    float* out = (float*)d_out;
    unsigned long long* slots = (unsigned long long*)d_ws;

    hipLaunchKernelGGL(snn_kernel, dim3(KB), dim3(NTHREADS), 0, stream,
                       x, noise, Win, Wout, pin, pout, l, stdv,
                       out, slots);
}